// Round 12
// baseline (1911.419 us; speedup 1.0000x reference)
//
#include <hip/hip_runtime.h>

// Decoder: 2-layer graph-conv LSTM, N=4096, B=32, C=16, H=64, K=3.
// supp GEMMs: 256x256 tile, BK=64, 8 waves, 16x16x32 MFMA, flow schedule.
// A operand read DIRECTLY from global (L1/L2-resident by XCD decode) into
// registers -> LDS port carries only B (reads+stage). 2 barriers/K-tile.
// Rectangle-preserving XCD decode. Fused bf16-MFMA gates + fp32 LSTM cell.

#define NN 4096
#define BB 32
#define HH 64

typedef __attribute__((ext_vector_type(8))) short short8;
typedef __attribute__((ext_vector_type(4))) float f32x4;

#define BARRIER asm volatile("s_barrier" ::: "memory")
#define VMCNT(n) asm volatile("s_waitcnt vmcnt(" #n ")" ::: "memory")

__device__ __forceinline__ unsigned short f2bf(float f) {
  unsigned int u = __float_as_uint(f);
  u += 0x7fffu + ((u >> 16) & 1u);
  return (unsigned short)(u >> 16);
}

// ---------------- G fp32 -> bf16 (vectorized) ----------------
__global__ __launch_bounds__(256) void cvt_kernel(const float* __restrict__ in,
                                                  unsigned short* __restrict__ out,
                                                  long n4) {
  long i = (long)blockIdx.x * 256 + threadIdx.x;
  if (i >= n4) return;
  float4 v = ((const float4*)in)[i];
  ushort4 o;
  o.x = f2bf(v.x); o.y = f2bf(v.y); o.z = f2bf(v.z); o.w = f2bf(v.w);
  ((ushort4*)out)[i] = o;
}

// ---------------- zero supp0 pad cols (240..255 of each 256-col row) -------
__global__ __launch_bounds__(256) void pad_zero(unsigned short* __restrict__ supp) {
  int i = blockIdx.x * 256 + threadIdx.x;   // 262144 short8 units
  int row = i >> 1;
  int half = i & 1;
  short8 z = {};
  *(short8*)&supp[(long)row * 256 + 240 + half * 8] = z;
}

// ---------------- pack comb0^T : [2560][4096] bf16 ----------------
__global__ __launch_bounds__(256) void pack_comb0(const float* __restrict__ x,
                                                  const float* __restrict__ h,
                                                  unsigned short* __restrict__ cT) {
  __shared__ float tile[80][65];
  const int m0 = blockIdx.x * 64;
  const int b = blockIdx.y;
  const int t = threadIdx.x;
  for (int i = t; i < 64 * 16; i += 256) {
    int m = i >> 4, p = i & 15;
    tile[p][m] = x[((long)b * NN + m0 + m) * 16 + p];
  }
  for (int i = t; i < 64 * 64; i += 256) {
    int m = i >> 6, p = i & 63;
    tile[16 + p][m] = h[((long)b * NN + m0 + m) * 64 + p];
  }
  __syncthreads();
  for (int i = t; i < 80 * 64; i += 256) {
    int p = i >> 6, m = i & 63;
    cT[((long)(b * 80 + p)) * NN + m0 + m] = f2bf(tile[p][m]);
  }
}

// ---------------- pack h1 into comb1^T cols [b*128+64 ..] ----------------
__global__ __launch_bounds__(256) void pack_h1(const float* __restrict__ h,
                                               unsigned short* __restrict__ cT) {
  __shared__ float tile[64][65];
  const int m0 = blockIdx.x * 64;
  const int b = blockIdx.y;
  const int t = threadIdx.x;
  for (int i = t; i < 64 * 64; i += 256) {
    int m = i >> 6, p = i & 63;
    tile[p][m] = h[((long)b * NN + m0 + m) * 64 + p];
  }
  __syncthreads();
  for (int i = t; i < 64 * 64; i += 256) {
    int p = i >> 6, m = i & 63;
    cT[((long)(b * 128 + 64 + p)) * NN + m0 + m] = f2bf(tile[p][m]);
  }
}

// ---------------- W [KP][256] fp32 -> Wt [256][SP] bf16 (zero-pad) --------
__global__ __launch_bounds__(256) void prep_wt(const float* __restrict__ W,
                                               unsigned short* __restrict__ Wt,
                                               int KP, int SP) {
  int c = blockIdx.x;
  for (int k = threadIdx.x; k < SP; k += blockDim.x)
    Wt[(long)c * SP + k] = (k < KP) ? f2bf(W[(long)k * 256 + c]) : (unsigned short)0;
}

// ---------------- supp GEMM: 256x256, BK=64, 8 waves, A-from-global -------
// out[b,n,k,p] = sum_m G[k][n][m] * combT[b*P+p][m]
// LDS 64 KiB = 2 dbuf x B(32K). A frags: global_load_dwordx4 -> regs.
// Per K-tile window: {A-loads c0; stage B(t+1); B ds_reads; 4 mmac clusters
// with A-loads interleaved}; VMCNT(0)+BARRIER at window end only.
// A locality: block's A panel = 2 MB, L2-resident (XCD decode); 4 waves per
// wm-half read identical 64B lines in the same window -> L1 hits.
template <int P, int SP, int RPK>
__global__ __launch_bounds__(512, 2) void gemm_ag(const unsigned short* __restrict__ Gb,
                                                  const unsigned short* __restrict__ BT,
                                                  unsigned short* __restrict__ supp) {
  __shared__ short lds[2][256 * 64];  // B only: 2 x 32 KiB
  const int t = threadIdx.x;
  const int w = t >> 6;
  const int lane = t & 63;
  const int lr = lane & 15;
  const int q = lane >> 4;
  const int wm = w >> 2;   // 0..1 : row half (128 rows)
  const int wn = w & 3;    // 0..3 : col band (64 cols)

  const int bid = blockIdx.x;
  const int xcd = bid & 7;
  const int rank = bid >> 3;
  const int kh = rank / RPK;
  const int jr = rank - kh * RPK;
  const int bm = xcd * 2 + (jr & 1);
  const int bc = jr >> 1;

  const short* Ag = (const short*)Gb + (long)kh * NN * NN + (long)bm * 256 * NN;
  const short* Bg = (const short*)BT + (long)bc * 256 * NN;

  // stage full B tile (256 x 64k) for K-tile kt into buf: 4 gload_lds/thread,
  // linear LDS dest + XOR-pre-swizzled global source (rule #21).
  auto stageB = [&](int buf, int kt) {
    const short* base = Bg + kt * 64;
#pragma unroll
    for (int j = 0; j < 4; ++j) {
      int L = j * 512 + t;
      int r = L >> 3;            // row 0..255
      int sl = L & 7;            // stored slot
      int s0 = sl ^ (r & 7);     // source slot
      short* dst = &lds[buf][(j * 512 + w * 64) * 8];
      __builtin_amdgcn_global_load_lds(
          (const __attribute__((address_space(1))) void*)(base + (long)r * NN + s0 * 8),
          (__attribute__((address_space(3))) void*)dst, 16, 0, 0);
    }
  };

  f32x4 acc[8][4] = {};
  short8 a4[4], bfr[4];

  auto loadA = [&](int tk, int u, int ks) {
#pragma unroll
    for (int mi = 0; mi < 4; ++mi) {
      int row = wm * 128 + (u * 4 + mi) * 16 + lr;
      a4[mi] = *(const short8*)(Ag + (long)row * NN + tk * 64 + ks * 32 + q * 8);
    }
  };
  auto rdB = [&](int buf, int ks) {
#pragma unroll
    for (int ni = 0; ni < 4; ++ni) {
      int row = wn * 64 + ni * 16 + lr;
      int slot = (ks * 4 + q) ^ (row & 7);
      bfr[ni] = *(const short8*)&lds[buf][row * 64 + slot * 8];
    }
  };
  auto mmac = [&](int u) {
    __builtin_amdgcn_s_setprio(1);
#pragma unroll
    for (int mi = 0; mi < 4; ++mi)
#pragma unroll
      for (int ni = 0; ni < 4; ++ni)
        acc[u * 4 + mi][ni] =
            __builtin_amdgcn_mfma_f32_16x16x32_bf16(a4[mi], bfr[ni], acc[u * 4 + mi][ni], 0, 0, 0);
    __builtin_amdgcn_s_setprio(0);
  };

  // prologue: B(0) -> buf0
  stageB(0, 0);
  VMCNT(0);
  BARRIER;

  for (int tk = 0; tk < 64; ++tk) {
    const int cur = tk & 1;
    // c0: A first (longest latency), then next-tile B stage, then B reads
    loadA(tk, 0, 0);
    if (tk + 1 < 64) stageB(cur ^ 1, tk + 1);
    rdB(cur, 0);
    mmac(0);
    loadA(tk, 1, 0);
    mmac(1);
    loadA(tk, 0, 1); rdB(cur, 1);
    mmac(0);
    loadA(tk, 1, 1);
    mmac(1);
    VMCNT(0);   // B(t+1) landed; A-loads already consumed
    BARRIER;
  }

  // Epilogue: D col=lane&15, row=(lane>>4)*4+i (verified); plain stores.
#pragma unroll
  for (int mi = 0; mi < 8; ++mi) {
#pragma unroll
    for (int ni = 0; ni < 4; ++ni) {
      int ccol = bc * 256 + wn * 64 + ni * 16 + lr;
      int b = ccol / P;
      int p = ccol - b * P;
#pragma unroll
      for (int i = 0; i < 4; ++i) {
        int n = bm * 256 + wm * 128 + mi * 16 + q * 4 + i;
        supp[((long)(b * NN + n)) * SP + kh * P + p] = f2bf(acc[mi][ni][i]);
      }
    }
  }
}

// ---------------- gates GEMM + LSTM cell, fused (32 tokens/wave) ----------
template <int SP, bool WBF, bool WH2>
__global__ __launch_bounds__(256) void gates_cell(const unsigned short* __restrict__ supp,
                                                  const unsigned short* __restrict__ Wt,
                                                  const float* __restrict__ bias,
                                                  const float* __restrict__ c_pre,
                                                  float* __restrict__ h_out,
                                                  float* __restrict__ c_out,
                                                  float* __restrict__ h_out2,
                                                  unsigned short* __restrict__ h_bf) {
  const int t = threadIdx.x;
  const int w = t >> 6;
  const int lane = t & 63;
  const int lr = lane & 15;
  const int q = lane >> 4;
  const long tok0 = (long)blockIdx.x * 128 + w * 32;
  f32x4 acc[2][16] = {};

  const short* sp0 = (const short*)supp + (tok0 + lr) * SP + q * 8;
  const short* sp1 = sp0 + 16 * SP;
  const short* wt = (const short*)Wt + (long)lr * SP + q * 8;
  for (int kk = 0; kk < SP / 32; ++kk) {
    short8 a0 = *(const short8*)(sp0 + kk * 32);
    short8 a1 = *(const short8*)(sp1 + kk * 32);
#pragma unroll
    for (int nf = 0; nf < 16; ++nf) {
      short8 b = *(const short8*)(wt + (long)nf * 16 * SP + kk * 32);
      acc[0][nf] = __builtin_amdgcn_mfma_f32_16x16x32_bf16(a0, b, acc[0][nf], 0, 0, 0);
      acc[1][nf] = __builtin_amdgcn_mfma_f32_16x16x32_bf16(a1, b, acc[1][nf], 0, 0, 0);
    }
  }
#pragma unroll
  for (int gi = 0; gi < 2; ++gi) {
#pragma unroll
    for (int i = 0; i < 4; ++i) {
      long tok = tok0 + gi * 16 + q * 4 + i;
      int bidx = (int)(tok >> 12);
      int n = (int)(tok & (NN - 1));
#pragma unroll
      for (int j = 0; j < 4; ++j) {
        int h = lr + 16 * j;
        float gi_ = acc[gi][j][i] + bias[h];
        float gf_ = acc[gi][j + 4][i] + bias[h + 64];
        float go_ = acc[gi][j + 8][i] + bias[h + 128];
        float gg_ = acc[gi][j + 12][i] + bias[h + 192];
        float cp = c_pre[tok * 64 + h];
        float ig = 1.f / (1.f + __expf(-gi_));
        float fg = 1.f / (1.f + __expf(-gf_));
        float og = 1.f / (1.f + __expf(-go_));
        float ct = fg * cp + ig * tanhf(gg_);
        float ht = og * tanhf(ct);
        c_out[tok * 64 + h] = ct;
        h_out[tok * 64 + h] = ht;
        if (WH2) h_out2[tok * 64 + h] = ht;
        if (WBF) h_bf[((long)(bidx * 128 + h)) * NN + n] = f2bf(ht);
      }
    }
  }
}

extern "C" void kernel_launch(void* const* d_in, const int* in_sizes, int n_in,
                              void* d_out, int out_size, void* d_ws, size_t ws_size,
                              hipStream_t stream) {
  const float* G  = (const float*)d_in[0];
  const float* x_t = (const float*)d_in[1];
  const float* h0 = (const float*)d_in[2];
  const float* h1 = (const float*)d_in[3];
  const float* c0 = (const float*)d_in[4];
  const float* c1 = (const float*)d_in[5];
  const float* W0 = (const float*)d_in[6];
  const float* b0 = (const float*)d_in[7];
  const float* W1 = (const float*)d_in[8];
  const float* b1 = (const float*)d_in[9];
  float* out = (float*)d_out;
  const long M = 8388608L;  // B*N*H

  char* ws = (char*)d_ws;
  unsigned short* Gb    = (unsigned short*)(ws);               // 100,663,296 B
  unsigned short* c0T   = (unsigned short*)(ws + 100663296L);  //  20,971,520 B
  unsigned short* c1T   = (unsigned short*)(ws + 121634816L);  //  33,554,432 B
  unsigned short* supp1 = (unsigned short*)(ws + 155189248L);  // 100,663,296 B
  unsigned short* supp0 = supp1;  // aliased (dead before gemm1 writes)
  unsigned short* Wt0   = (unsigned short*)(ws + 255852544L);
  unsigned short* Wt1   = (unsigned short*)(ws + 255983616L);

  // zero layer-0 supp pad cols only (4 MB instead of 64 MB memset)
  pad_zero<<<1024, 256, 0, stream>>>(supp0);

  cvt_kernel<<<49152, 256, 0, stream>>>(G, Gb, 12582912L);
  pack_comb0<<<dim3(64, 32), 256, 0, stream>>>(x_t, h0, c0T);
  pack_h1<<<dim3(64, 32), 256, 0, stream>>>(h1, c1T);
  prep_wt<<<dim3(256), 256, 0, stream>>>(W0, Wt0, 240, 256);
  prep_wt<<<dim3(256), 256, 0, stream>>>(W1, Wt1, 384, 384);

  // layer 0: 16 bm x 10 bc x 3 kh = 480 blocks; RPK = 20 ranks per kh
  gemm_ag<80, 256, 20><<<480, 512, 0, stream>>>(Gb, c0T, supp0);
  gates_cell<256, true, false><<<1024, 256, 0, stream>>>(
      supp0, Wt0, b0, c0, out + M, out + 3 * M, nullptr, c1T);
  // layer 1: 16 bm x 16 bc x 3 kh = 768 blocks; RPK = 32
  gemm_ag<128, 384, 32><<<768, 512, 0, stream>>>(Gb, c1T, supp1);
  gates_cell<384, false, true><<<1024, 256, 0, stream>>>(
      supp1, Wt1, b1, c1, out, out + 4 * M, out + 2 * M, nullptr);
}

// Round 14
// 1391.951 us; speedup vs baseline: 1.3732x; 1.3732x over previous
//
#include <hip/hip_runtime.h>

// Decoder: 2-layer graph-conv LSTM, N=4096, B=32, C=16, H=64, K=3.
// supp GEMMs: 256x256 tile, BK=64, 8 waves, 16x16x32 MFMA.
// A (=G) pre-converted to FRAGMENT-MAJOR bf16 by cvt_fm, so A-frag loads are
// single coalesced global_load_dwordx4 (1KB/wave) -> vmem pipe; LDS carries
// only B (stage+read) -> MFMA wall is the lone max.
// R13 bug: Ag base missed the x64 lane-dim factor; fixed below.
// Rectangle-preserving XCD decode. Fused bf16-MFMA gates + fp32 LSTM cell.

#define NN 4096
#define BB 32
#define HH 64

typedef __attribute__((ext_vector_type(8))) short short8;
typedef __attribute__((ext_vector_type(4))) float f32x4;

#define BARRIER asm volatile("s_barrier" ::: "memory")
#define VMCNT(n) asm volatile("s_waitcnt vmcnt(" #n ")" ::: "memory")

__device__ __forceinline__ unsigned short f2bf(float f) {
  unsigned int u = __float_as_uint(f);
  u += 0x7fffu + ((u >> 16) & 1u);
  return (unsigned short)(u >> 16);
}

// ---------------- G fp32 -> frag-major bf16 ----------------
// unit16B ((kh*256+nb)*128+ks)*64+lane holds G[kh][nb*16+(lane&15)]
// [ks*32+(lane>>4)*8+j], j=0..7  (the verified 16x16x32 A lane map).
__global__ __launch_bounds__(256) void cvt_fm(const float* __restrict__ G,
                                              unsigned short* __restrict__ A) {
  __shared__ unsigned short st[16][528];  // 512 + pad16 (row base stays 16B-aligned)
  const int t = threadIdx.x;
  const int kc = blockIdx.x;   // 0..7 : 512-k chunk
  const int nb = blockIdx.y;   // 0..255 : 16-row block
  const int kh = blockIdx.z;
  const float* src = G + ((long)kh * NN + nb * 16) * NN + kc * 512;
#pragma unroll
  for (int i = 0; i < 8; ++i) {
    int flat = i * 256 + t;        // 2048 float4
    int row = flat >> 7;
    int kq = flat & 127;
    float4 v = *(const float4*)(src + (long)row * NN + kq * 4);
    unsigned short* d = &st[row][kq * 4];
    d[0] = f2bf(v.x); d[1] = f2bf(v.y); d[2] = f2bf(v.z); d[3] = f2bf(v.w);
  }
  __syncthreads();
  unsigned short* dst = A + ((long)(kh * 256 + nb) * 128 + kc * 16) * 64 * 8;
#pragma unroll
  for (int i = 0; i < 4; ++i) {
    int u = i * 256 + t;           // 1024 units of 16B
    int ksl = u >> 6;              // k-slice within chunk
    int l = u & 63;                // lane slot
    short8 v = *(const short8*)&st[l & 15][ksl * 32 + (l >> 4) * 8];
    *(short8*)(dst + (long)u * 8) = v;   // coalesced
  }
}

// ---------------- zero supp0 pad cols (240..255 of each 256-col row) -------
__global__ __launch_bounds__(256) void pad_zero(unsigned short* __restrict__ supp) {
  int i = blockIdx.x * 256 + threadIdx.x;   // 262144 short8 units
  int row = i >> 1;
  int half = i & 1;
  short8 z = {};
  *(short8*)&supp[(long)row * 256 + 240 + half * 8] = z;
}

// ---------------- pack comb0^T : [2560][4096] bf16 ----------------
__global__ __launch_bounds__(256) void pack_comb0(const float* __restrict__ x,
                                                  const float* __restrict__ h,
                                                  unsigned short* __restrict__ cT) {
  __shared__ float tile[80][65];
  const int m0 = blockIdx.x * 64;
  const int b = blockIdx.y;
  const int t = threadIdx.x;
  for (int i = t; i < 64 * 16; i += 256) {
    int m = i >> 4, p = i & 15;
    tile[p][m] = x[((long)b * NN + m0 + m) * 16 + p];
  }
  for (int i = t; i < 64 * 64; i += 256) {
    int m = i >> 6, p = i & 63;
    tile[16 + p][m] = h[((long)b * NN + m0 + m) * 64 + p];
  }
  __syncthreads();
  for (int i = t; i < 80 * 64; i += 256) {
    int p = i >> 6, m = i & 63;
    cT[((long)(b * 80 + p)) * NN + m0 + m] = f2bf(tile[p][m]);
  }
}

// ---------------- pack h1 into comb1^T cols [b*128+64 ..] ----------------
__global__ __launch_bounds__(256) void pack_h1(const float* __restrict__ h,
                                               unsigned short* __restrict__ cT) {
  __shared__ float tile[64][65];
  const int m0 = blockIdx.x * 64;
  const int b = blockIdx.y;
  const int t = threadIdx.x;
  for (int i = t; i < 64 * 64; i += 256) {
    int m = i >> 6, p = i & 63;
    tile[p][m] = h[((long)b * NN + m0 + m) * 64 + p];
  }
  __syncthreads();
  for (int i = t; i < 64 * 64; i += 256) {
    int p = i >> 6, m = i & 63;
    cT[((long)(b * 128 + 64 + p)) * NN + m0 + m] = f2bf(tile[p][m]);
  }
}

// ---------------- W [KP][256] fp32 -> Wt [256][SP] bf16 (zero-pad) --------
__global__ __launch_bounds__(256) void prep_wt(const float* __restrict__ W,
                                               unsigned short* __restrict__ Wt,
                                               int KP, int SP) {
  int c = blockIdx.x;
  for (int k = threadIdx.x; k < SP; k += blockDim.x)
    Wt[(long)c * SP + k] = (k < KP) ? f2bf(W[(long)k * 256 + c]) : (unsigned short)0;
}

// ---------------- supp GEMM: 256x256, BK=64, 8 waves, A frag-major global --
// out[b,n,k,p] = sum_m G[k][n][m] * combT[b*P+p][m]
// LDS 64 KiB = 2 dbuf x B(32K). A frags: ONE coalesced dwordx4 per frag.
// Per K-tile window: {A-loads + stage B(t+1) + B ds_reads + 4 mmac clusters
// interleaved}; VMCNT(0)+BARRIER at window end.
template <int P, int SP, int RPK>
__global__ __launch_bounds__(512, 2) void gemm_ag(const unsigned short* __restrict__ Afm,
                                                  const unsigned short* __restrict__ BT,
                                                  unsigned short* __restrict__ supp) {
  __shared__ short lds[2][256 * 64];  // B only: 2 x 32 KiB
  const int t = threadIdx.x;
  const int w = t >> 6;
  const int lane = t & 63;
  const int lr = lane & 15;
  const int q = lane >> 4;
  const int wm = w >> 2;   // 0..1 : row half (128 rows)
  const int wn = w & 3;    // 0..3 : col band (64 cols)

  const int bid = blockIdx.x;
  const int xcd = bid & 7;
  const int rank = bid >> 3;
  const int kh = rank / RPK;
  const int jr = rank - kh * RPK;
  const int bm = xcd * 2 + (jr & 1);
  const int bc = jr >> 1;

  // FIX (R13): base unit = (kh*256 + bm*16 + wm*8) * 128 * 64 + lane
  const short* Ag = (const short*)Afm +
                    (((long)(kh * 256 + bm * 16 + wm * 8) * 128) * 64 + lane) * 8;
  const short* Bg = (const short*)BT + (long)bc * 256 * NN;

  // stage full B tile (256 x 64k) for K-tile kt into buf: 4 gload_lds/thread,
  // linear LDS dest + XOR-pre-swizzled global source (rule #21).
  auto stageB = [&](int buf, int kt) {
    const short* base = Bg + kt * 64;
#pragma unroll
    for (int j = 0; j < 4; ++j) {
      int L = j * 512 + t;
      int r = L >> 3;            // row 0..255
      int sl = L & 7;            // stored slot
      int s0 = sl ^ (r & 7);     // source slot
      short* dst = &lds[buf][(j * 512 + w * 64) * 8];
      __builtin_amdgcn_global_load_lds(
          (const __attribute__((address_space(1))) void*)(base + (long)r * NN + s0 * 8),
          (__attribute__((address_space(3))) void*)dst, 16, 0, 0);
    }
  };

  f32x4 acc[8][4] = {};
  short8 a4[4], bfr[4];

  // A frag (u,mi) at K-tile tk, k-slice ks: +((u*4+mi)*128 + tk*2+ks)*64 units
  auto loadA = [&](int tk, int u, int ks) {
#pragma unroll
    for (int mi = 0; mi < 4; ++mi) {
      long off = ((long)(u * 4 + mi) * 128 + (tk * 2 + ks)) * 64 * 8;
      a4[mi] = *(const short8*)(Ag + off);
    }
  };
  auto rdB = [&](int buf, int ks) {
#pragma unroll
    for (int ni = 0; ni < 4; ++ni) {
      int row = wn * 64 + ni * 16 + lr;
      int slot = (ks * 4 + q) ^ (row & 7);
      bfr[ni] = *(const short8*)&lds[buf][row * 64 + slot * 8];
    }
  };
  auto mmac = [&](int u) {
    __builtin_amdgcn_s_setprio(1);
#pragma unroll
    for (int mi = 0; mi < 4; ++mi)
#pragma unroll
      for (int ni = 0; ni < 4; ++ni)
        acc[u * 4 + mi][ni] =
            __builtin_amdgcn_mfma_f32_16x16x32_bf16(a4[mi], bfr[ni], acc[u * 4 + mi][ni], 0, 0, 0);
    __builtin_amdgcn_s_setprio(0);
  };

  // prologue: B(0) -> buf0
  stageB(0, 0);
  VMCNT(0);
  BARRIER;

  for (int tk = 0; tk < 64; ++tk) {
    const int cur = tk & 1;
    loadA(tk, 0, 0);
    if (tk + 1 < 64) stageB(cur ^ 1, tk + 1);
    rdB(cur, 0);
    mmac(0);
    loadA(tk, 1, 0);
    mmac(1);
    loadA(tk, 0, 1); rdB(cur, 1);
    mmac(0);
    loadA(tk, 1, 1);
    mmac(1);
    VMCNT(0);   // B(t+1) landed; A-loads already consumed
    BARRIER;
  }

  // Epilogue: D col=lane&15, row=(lane>>4)*4+i (verified); plain stores.
#pragma unroll
  for (int mi = 0; mi < 8; ++mi) {
#pragma unroll
    for (int ni = 0; ni < 4; ++ni) {
      int ccol = bc * 256 + wn * 64 + ni * 16 + lr;
      int b = ccol / P;
      int p = ccol - b * P;
#pragma unroll
      for (int i = 0; i < 4; ++i) {
        int n = bm * 256 + wm * 128 + mi * 16 + q * 4 + i;
        supp[((long)(b * NN + n)) * SP + kh * P + p] = f2bf(acc[mi][ni][i]);
      }
    }
  }
}

// ---------------- gates GEMM + LSTM cell, fused (32 tokens/wave) ----------
template <int SP, bool WBF, bool WH2>
__global__ __launch_bounds__(256) void gates_cell(const unsigned short* __restrict__ supp,
                                                  const unsigned short* __restrict__ Wt,
                                                  const float* __restrict__ bias,
                                                  const float* __restrict__ c_pre,
                                                  float* __restrict__ h_out,
                                                  float* __restrict__ c_out,
                                                  float* __restrict__ h_out2,
                                                  unsigned short* __restrict__ h_bf) {
  const int t = threadIdx.x;
  const int w = t >> 6;
  const int lane = t & 63;
  const int lr = lane & 15;
  const int q = lane >> 4;
  const long tok0 = (long)blockIdx.x * 128 + w * 32;
  f32x4 acc[2][16] = {};

  const short* sp0 = (const short*)supp + (tok0 + lr) * SP + q * 8;
  const short* sp1 = sp0 + 16 * SP;
  const short* wt = (const short*)Wt + (long)lr * SP + q * 8;
  for (int kk = 0; kk < SP / 32; ++kk) {
    short8 a0 = *(const short8*)(sp0 + kk * 32);
    short8 a1 = *(const short8*)(sp1 + kk * 32);
#pragma unroll
    for (int nf = 0; nf < 16; ++nf) {
      short8 b = *(const short8*)(wt + (long)nf * 16 * SP + kk * 32);
      acc[0][nf] = __builtin_amdgcn_mfma_f32_16x16x32_bf16(a0, b, acc[0][nf], 0, 0, 0);
      acc[1][nf] = __builtin_amdgcn_mfma_f32_16x16x32_bf16(a1, b, acc[1][nf], 0, 0, 0);
    }
  }
#pragma unroll
  for (int gi = 0; gi < 2; ++gi) {
#pragma unroll
    for (int i = 0; i < 4; ++i) {
      long tok = tok0 + gi * 16 + q * 4 + i;
      int bidx = (int)(tok >> 12);
      int n = (int)(tok & (NN - 1));
#pragma unroll
      for (int j = 0; j < 4; ++j) {
        int h = lr + 16 * j;
        float gi_ = acc[gi][j][i] + bias[h];
        float gf_ = acc[gi][j + 4][i] + bias[h + 64];
        float go_ = acc[gi][j + 8][i] + bias[h + 128];
        float gg_ = acc[gi][j + 12][i] + bias[h + 192];
        float cp = c_pre[tok * 64 + h];
        float ig = 1.f / (1.f + __expf(-gi_));
        float fg = 1.f / (1.f + __expf(-gf_));
        float og = 1.f / (1.f + __expf(-go_));
        float ct = fg * cp + ig * tanhf(gg_);
        float ht = og * tanhf(ct);
        c_out[tok * 64 + h] = ct;
        h_out[tok * 64 + h] = ht;
        if (WH2) h_out2[tok * 64 + h] = ht;
        if (WBF) h_bf[((long)(bidx * 128 + h)) * NN + n] = f2bf(ht);
      }
    }
  }
}

extern "C" void kernel_launch(void* const* d_in, const int* in_sizes, int n_in,
                              void* d_out, int out_size, void* d_ws, size_t ws_size,
                              hipStream_t stream) {
  const float* G  = (const float*)d_in[0];
  const float* x_t = (const float*)d_in[1];
  const float* h0 = (const float*)d_in[2];
  const float* h1 = (const float*)d_in[3];
  const float* c0 = (const float*)d_in[4];
  const float* c1 = (const float*)d_in[5];
  const float* W0 = (const float*)d_in[6];
  const float* b0 = (const float*)d_in[7];
  const float* W1 = (const float*)d_in[8];
  const float* b1 = (const float*)d_in[9];
  float* out = (float*)d_out;
  const long M = 8388608L;  // B*N*H

  char* ws = (char*)d_ws;
  unsigned short* Gb    = (unsigned short*)(ws);               // 100,663,296 B (frag-major)
  unsigned short* c0T   = (unsigned short*)(ws + 100663296L);  //  20,971,520 B
  unsigned short* c1T   = (unsigned short*)(ws + 121634816L);  //  33,554,432 B
  unsigned short* supp1 = (unsigned short*)(ws + 155189248L);  // 100,663,296 B
  unsigned short* supp0 = supp1;  // aliased (dead before gemm1 writes)
  unsigned short* Wt0   = (unsigned short*)(ws + 255852544L);
  unsigned short* Wt1   = (unsigned short*)(ws + 255983616L);

  // zero layer-0 supp pad cols only (4 MB instead of 64 MB memset)
  pad_zero<<<1024, 256, 0, stream>>>(supp0);

  cvt_fm<<<dim3(8, 256, 3), 256, 0, stream>>>(G, Gb);
  pack_comb0<<<dim3(64, 32), 256, 0, stream>>>(x_t, h0, c0T);
  pack_h1<<<dim3(64, 32), 256, 0, stream>>>(h1, c1T);
  prep_wt<<<dim3(256), 256, 0, stream>>>(W0, Wt0, 240, 256);
  prep_wt<<<dim3(256), 256, 0, stream>>>(W1, Wt1, 384, 384);

  // layer 0: 16 bm x 10 bc x 3 kh = 480 blocks; RPK = 20 ranks per kh
  gemm_ag<80, 256, 20><<<480, 512, 0, stream>>>(Gb, c0T, supp0);
  gates_cell<256, true, false><<<1024, 256, 0, stream>>>(
      supp0, Wt0, b0, c0, out + M, out + 3 * M, nullptr, c1T);
  // layer 1: 16 bm x 16 bc x 3 kh = 768 blocks; RPK = 32
  gemm_ag<128, 384, 32><<<768, 512, 0, stream>>>(Gb, c1T, supp1);
  gates_cell<384, false, true><<<1024, 256, 0, stream>>>(
      supp1, Wt1, b1, c1, out, out + 4 * M, out + 2 * M, nullptr);
}

// Round 15
// 1067.416 us; speedup vs baseline: 1.7907x; 1.3040x over previous
//
#include <hip/hip_runtime.h>

// Decoder: 2-layer graph-conv LSTM, N=4096, B=32, C=16, H=64, K=3.
// supp GEMMs: 256x256 tile, BK=64, 8 waves, 16x16x32 MFMA, "flow" schedule
// (R11-verified best: 1.25 PF, MfmaUtil 57%): 1 barrier per K-tile; within a
// window, ds_reads / MFMA clusters / next-tile stages interleave in-order.
// This round: setprio REMOVED (m190: hurts lockstep GEMM), last iter peeled.
// Rectangle-preserving XCD decode. Fused bf16-MFMA gates + fp32 LSTM cell.

#define NN 4096
#define BB 32
#define HH 64

typedef __attribute__((ext_vector_type(8))) short short8;
typedef __attribute__((ext_vector_type(4))) float f32x4;

#define BARRIER asm volatile("s_barrier" ::: "memory")
#define VMCNT(n) asm volatile("s_waitcnt vmcnt(" #n ")" ::: "memory")

__device__ __forceinline__ unsigned short f2bf(float f) {
  unsigned int u = __float_as_uint(f);
  u += 0x7fffu + ((u >> 16) & 1u);
  return (unsigned short)(u >> 16);
}

// ---------------- G fp32 -> bf16 (vectorized) ----------------
__global__ __launch_bounds__(256) void cvt_kernel(const float* __restrict__ in,
                                                  unsigned short* __restrict__ out,
                                                  long n4) {
  long i = (long)blockIdx.x * 256 + threadIdx.x;
  if (i >= n4) return;
  float4 v = ((const float4*)in)[i];
  ushort4 o;
  o.x = f2bf(v.x); o.y = f2bf(v.y); o.z = f2bf(v.z); o.w = f2bf(v.w);
  ((ushort4*)out)[i] = o;
}

// ---------------- zero supp0 pad cols (240..255 of each 256-col row) -------
__global__ __launch_bounds__(256) void pad_zero(unsigned short* __restrict__ supp) {
  int i = blockIdx.x * 256 + threadIdx.x;   // 262144 short8 units
  int row = i >> 1;
  int half = i & 1;
  short8 z = {};
  *(short8*)&supp[(long)row * 256 + 240 + half * 8] = z;
}

// ---------------- pack comb0^T : [2560][4096] bf16 ----------------
__global__ __launch_bounds__(256) void pack_comb0(const float* __restrict__ x,
                                                  const float* __restrict__ h,
                                                  unsigned short* __restrict__ cT) {
  __shared__ float tile[80][65];
  const int m0 = blockIdx.x * 64;
  const int b = blockIdx.y;
  const int t = threadIdx.x;
  for (int i = t; i < 64 * 16; i += 256) {
    int m = i >> 4, p = i & 15;
    tile[p][m] = x[((long)b * NN + m0 + m) * 16 + p];
  }
  for (int i = t; i < 64 * 64; i += 256) {
    int m = i >> 6, p = i & 63;
    tile[16 + p][m] = h[((long)b * NN + m0 + m) * 64 + p];
  }
  __syncthreads();
  for (int i = t; i < 80 * 64; i += 256) {
    int p = i >> 6, m = i & 63;
    cT[((long)(b * 80 + p)) * NN + m0 + m] = f2bf(tile[p][m]);
  }
}

// ---------------- pack h1 into comb1^T cols [b*128+64 ..] ----------------
__global__ __launch_bounds__(256) void pack_h1(const float* __restrict__ h,
                                               unsigned short* __restrict__ cT) {
  __shared__ float tile[64][65];
  const int m0 = blockIdx.x * 64;
  const int b = blockIdx.y;
  const int t = threadIdx.x;
  for (int i = t; i < 64 * 64; i += 256) {
    int m = i >> 6, p = i & 63;
    tile[p][m] = h[((long)b * NN + m0 + m) * 64 + p];
  }
  __syncthreads();
  for (int i = t; i < 64 * 64; i += 256) {
    int p = i >> 6, m = i & 63;
    cT[((long)(b * 128 + 64 + p)) * NN + m0 + m] = f2bf(tile[p][m]);
  }
}

// ---------------- W [KP][256] fp32 -> Wt [256][SP] bf16 (zero-pad) --------
__global__ __launch_bounds__(256) void prep_wt(const float* __restrict__ W,
                                               unsigned short* __restrict__ Wt,
                                               int KP, int SP) {
  int c = blockIdx.x;
  for (int k = threadIdx.x; k < SP; k += blockDim.x)
    Wt[(long)c * SP + k] = (k < KP) ? f2bf(W[(long)k * 256 + c]) : (unsigned short)0;
}

// ---------------- supp GEMM: 256x256, BK=64, 8 waves, flow schedule --------
// out[b,n,k,p] = sum_m G[k][n][m] * combT[b*P+p][m]
// LDS 128 KiB = 2 dbuf x (A 32K + B 32K). Per K-tile window: all 24 ds_reads
// + 4 mmac clusters interleaved + 4 half-tile stages for t+1; VMCNT(0)+BARRIER
// at tile end only (forced by 2-buffer: stage(t+1) must land inside window t).
template <int P, int SP, int RPK>
__global__ __launch_bounds__(512, 2) void gemm_flow(const unsigned short* __restrict__ Gb,
                                                    const unsigned short* __restrict__ BT,
                                                    unsigned short* __restrict__ supp) {
  __shared__ short lds[2][2][256 * 64];  // 128 KiB
  const int t = threadIdx.x;
  const int w = t >> 6;
  const int lane = t & 63;
  const int lr = lane & 15;
  const int q = lane >> 4;
  const int wm = w >> 2;   // 0..1 : row half (128 rows)
  const int wn = w & 3;    // 0..3 : col band (64 cols)

  const int bid = blockIdx.x;
  const int xcd = bid & 7;
  const int rank = bid >> 3;
  const int kh = rank / RPK;
  const int jr = rank - kh * RPK;
  const int bm = xcd * 2 + (jr & 1);
  const int bc = jr >> 1;

  const short* Ag = (const short*)Gb + (long)kh * NN * NN + (long)bm * 256 * NN;
  const short* Bg = (const short*)BT + (long)bc * 256 * NN;

  // stage one row-half (128 rows x 64 k); linear LDS dest + XOR-swizzled src.
  auto stage = [&](int mat, int buf, int kt, int half) {
    const short* base = (mat ? Bg : Ag) + kt * 64;
#pragma unroll
    for (int j = 0; j < 2; ++j) {
      int L = j * 512 + t;
      int rl = L >> 3;
      int sl = L & 7;
      int r = half * 128 + rl;
      int s0 = sl ^ (r & 7);
      short* dst = &lds[buf][mat][(half * 1024 + j * 512 + w * 64) * 8];
      __builtin_amdgcn_global_load_lds(
          (const __attribute__((address_space(1))) void*)(base + (long)r * NN + s0 * 8),
          (__attribute__((address_space(3))) void*)dst, 16, 0, 0);
    }
  };

  f32x4 acc[8][4] = {};
  short8 a4[4], bfr[4];

  auto rdA = [&](int buf, int u, int ks) {
#pragma unroll
    for (int mi = 0; mi < 4; ++mi) {
      int row = wm * 128 + (u * 4 + mi) * 16 + lr;
      int slot = (ks * 4 + q) ^ (row & 7);
      a4[mi] = *(const short8*)&lds[buf][0][row * 64 + slot * 8];
    }
  };
  auto rdB = [&](int buf, int ks) {
#pragma unroll
    for (int ni = 0; ni < 4; ++ni) {
      int row = wn * 64 + ni * 16 + lr;
      int slot = (ks * 4 + q) ^ (row & 7);
      bfr[ni] = *(const short8*)&lds[buf][1][row * 64 + slot * 8];
    }
  };
  auto mmac = [&](int u) {
    // no setprio: lockstep GEMM has no wave role-split (m190: setprio hurts)
#pragma unroll
    for (int mi = 0; mi < 4; ++mi)
#pragma unroll
      for (int ni = 0; ni < 4; ++ni)
        acc[u * 4 + mi][ni] =
            __builtin_amdgcn_mfma_f32_16x16x32_bf16(a4[mi], bfr[ni], acc[u * 4 + mi][ni], 0, 0, 0);
  };

  // prologue: tile0 (all 4 halves) -> buf0.
  stage(0, 0, 0, 0); stage(0, 0, 0, 1);
  stage(1, 0, 0, 0); stage(1, 0, 0, 1);
  VMCNT(0);
  BARRIER;

  for (int g = 0; g < 31; ++g) {
    const int tk = 2 * g;
    // ---- tile tk (buf0); stage tile tk+1 -> buf1 ----
    rdB(0, 0); rdA(0, 0, 0);
    stage(0, 1, tk + 1, 0); stage(0, 1, tk + 1, 1);   // A(t+1)
    mmac(0);
    rdA(0, 1, 0);
    stage(1, 1, tk + 1, 0);                            // Btop(t+1)
    mmac(1);
    rdB(0, 1); rdA(0, 0, 1);
    stage(1, 1, tk + 1, 1);                            // Bbot(t+1)
    mmac(0);
    rdA(0, 1, 1);
    mmac(1);
    VMCNT(0);
    BARRIER;
    // ---- tile tk+1 (buf1); stage tile tk+2 -> buf0 ----
    rdB(1, 0); rdA(1, 0, 0);
    stage(0, 0, tk + 2, 0); stage(0, 0, tk + 2, 1);
    mmac(0);
    rdA(1, 1, 0);
    stage(1, 0, tk + 2, 0);
    mmac(1);
    rdB(1, 1); rdA(1, 0, 1);
    stage(1, 0, tk + 2, 1);
    mmac(0);
    rdA(1, 1, 1);
    mmac(1);
    VMCNT(0);
    BARRIER;
  }
  // ---- peeled tail: tile 62 (buf0) stages tile 63; tile 63 (buf1) no stage
  rdB(0, 0); rdA(0, 0, 0);
  stage(0, 1, 63, 0); stage(0, 1, 63, 1);
  mmac(0);
  rdA(0, 1, 0);
  stage(1, 1, 63, 0);
  mmac(1);
  rdB(0, 1); rdA(0, 0, 1);
  stage(1, 1, 63, 1);
  mmac(0);
  rdA(0, 1, 1);
  mmac(1);
  VMCNT(0);
  BARRIER;
  rdB(1, 0); rdA(1, 0, 0);
  mmac(0);
  rdA(1, 1, 0);
  mmac(1);
  rdB(1, 1); rdA(1, 0, 1);
  mmac(0);
  rdA(1, 1, 1);
  mmac(1);

  // Epilogue: D col=lane&15, row=(lane>>4)*4+i (verified); plain stores.
#pragma unroll
  for (int mi = 0; mi < 8; ++mi) {
#pragma unroll
    for (int ni = 0; ni < 4; ++ni) {
      int ccol = bc * 256 + wn * 64 + ni * 16 + lr;
      int b = ccol / P;
      int p = ccol - b * P;
#pragma unroll
      for (int i = 0; i < 4; ++i) {
        int n = bm * 256 + wm * 128 + mi * 16 + q * 4 + i;
        supp[((long)(b * NN + n)) * SP + kh * P + p] = f2bf(acc[mi][ni][i]);
      }
    }
  }
}

// ---------------- gates GEMM + LSTM cell, fused (32 tokens/wave) ----------
template <int SP, bool WBF, bool WH2>
__global__ __launch_bounds__(256) void gates_cell(const unsigned short* __restrict__ supp,
                                                  const unsigned short* __restrict__ Wt,
                                                  const float* __restrict__ bias,
                                                  const float* __restrict__ c_pre,
                                                  float* __restrict__ h_out,
                                                  float* __restrict__ c_out,
                                                  float* __restrict__ h_out2,
                                                  unsigned short* __restrict__ h_bf) {
  const int t = threadIdx.x;
  const int w = t >> 6;
  const int lane = t & 63;
  const int lr = lane & 15;
  const int q = lane >> 4;
  const long tok0 = (long)blockIdx.x * 128 + w * 32;
  f32x4 acc[2][16] = {};

  const short* sp0 = (const short*)supp + (tok0 + lr) * SP + q * 8;
  const short* sp1 = sp0 + 16 * SP;
  const short* wt = (const short*)Wt + (long)lr * SP + q * 8;
  for (int kk = 0; kk < SP / 32; ++kk) {
    short8 a0 = *(const short8*)(sp0 + kk * 32);
    short8 a1 = *(const short8*)(sp1 + kk * 32);
#pragma unroll
    for (int nf = 0; nf < 16; ++nf) {
      short8 b = *(const short8*)(wt + (long)nf * 16 * SP + kk * 32);
      acc[0][nf] = __builtin_amdgcn_mfma_f32_16x16x32_bf16(a0, b, acc[0][nf], 0, 0, 0);
      acc[1][nf] = __builtin_amdgcn_mfma_f32_16x16x32_bf16(a1, b, acc[1][nf], 0, 0, 0);
    }
  }
#pragma unroll
  for (int gi = 0; gi < 2; ++gi) {
#pragma unroll
    for (int i = 0; i < 4; ++i) {
      long tok = tok0 + gi * 16 + q * 4 + i;
      int bidx = (int)(tok >> 12);
      int n = (int)(tok & (NN - 1));
#pragma unroll
      for (int j = 0; j < 4; ++j) {
        int h = lr + 16 * j;
        float gi_ = acc[gi][j][i] + bias[h];
        float gf_ = acc[gi][j + 4][i] + bias[h + 64];
        float go_ = acc[gi][j + 8][i] + bias[h + 128];
        float gg_ = acc[gi][j + 12][i] + bias[h + 192];
        float cp = c_pre[tok * 64 + h];
        float ig = 1.f / (1.f + __expf(-gi_));
        float fg = 1.f / (1.f + __expf(-gf_));
        float og = 1.f / (1.f + __expf(-go_));
        float ct = fg * cp + ig * tanhf(gg_);
        float ht = og * tanhf(ct);
        c_out[tok * 64 + h] = ct;
        h_out[tok * 64 + h] = ht;
        if (WH2) h_out2[tok * 64 + h] = ht;
        if (WBF) h_bf[((long)(bidx * 128 + h)) * NN + n] = f2bf(ht);
      }
    }
  }
}

extern "C" void kernel_launch(void* const* d_in, const int* in_sizes, int n_in,
                              void* d_out, int out_size, void* d_ws, size_t ws_size,
                              hipStream_t stream) {
  const float* G  = (const float*)d_in[0];
  const float* x_t = (const float*)d_in[1];
  const float* h0 = (const float*)d_in[2];
  const float* h1 = (const float*)d_in[3];
  const float* c0 = (const float*)d_in[4];
  const float* c1 = (const float*)d_in[5];
  const float* W0 = (const float*)d_in[6];
  const float* b0 = (const float*)d_in[7];
  const float* W1 = (const float*)d_in[8];
  const float* b1 = (const float*)d_in[9];
  float* out = (float*)d_out;
  const long M = 8388608L;  // B*N*H

  char* ws = (char*)d_ws;
  unsigned short* Gb    = (unsigned short*)(ws);               // 100,663,296 B
  unsigned short* c0T   = (unsigned short*)(ws + 100663296L);  //  20,971,520 B
  unsigned short* c1T   = (unsigned short*)(ws + 121634816L);  //  33,554,432 B
  unsigned short* supp1 = (unsigned short*)(ws + 155189248L);  // 100,663,296 B
  unsigned short* supp0 = supp1;  // aliased (dead before gemm1 writes)
  unsigned short* Wt0   = (unsigned short*)(ws + 255852544L);
  unsigned short* Wt1   = (unsigned short*)(ws + 255983616L);

  // zero layer-0 supp pad cols only (4 MB instead of 64 MB memset)
  pad_zero<<<1024, 256, 0, stream>>>(supp0);

  cvt_kernel<<<49152, 256, 0, stream>>>(G, Gb, 12582912L);
  pack_comb0<<<dim3(64, 32), 256, 0, stream>>>(x_t, h0, c0T);
  pack_h1<<<dim3(64, 32), 256, 0, stream>>>(h1, c1T);
  prep_wt<<<dim3(256), 256, 0, stream>>>(W0, Wt0, 240, 256);
  prep_wt<<<dim3(256), 256, 0, stream>>>(W1, Wt1, 384, 384);

  // layer 0: 16 bm x 10 bc x 3 kh = 480 blocks; RPK = 20 ranks per kh
  gemm_flow<80, 256, 20><<<480, 512, 0, stream>>>(Gb, c0T, supp0);
  gates_cell<256, true, false><<<1024, 256, 0, stream>>>(
      supp0, Wt0, b0, c0, out + M, out + 3 * M, nullptr, c1T);
  // layer 1: 16 bm x 16 bc x 3 kh = 768 blocks; RPK = 32
  gemm_flow<128, 384, 32><<<768, 512, 0, stream>>>(Gb, c1T, supp1);
  gates_cell<384, false, true><<<1024, 256, 0, stream>>>(
      supp1, Wt1, b1, c1, out, out + 4 * M, out + 2 * M, nullptr);
}

// Round 16
// 924.491 us; speedup vs baseline: 2.0675x; 1.1546x over previous
//
#include <hip/hip_runtime.h>

// Decoder: 2-layer graph-conv LSTM, N=4096, B=32, C=16, H=64, K=3.
// EXACT REVERT to R11 (best verified: 923 us, MfmaUtil 57%, gemm ~1.25 PF):
// supp GEMMs: 256x256 tile, BK=64, 8 waves, 16x16x32 MFMA, "flow" schedule:
// 2 barriers per K-tile; within a tile, ds_reads and MFMA clusters interleave
// in-order per wave; stages for tile t+1 issue at tile-t start and drain
// (VMCNT 0) at the tile boundary. setprio kept (flow windows have wave
// role-split -> T5 applies; R15 ablation: removing it cost 15pts MfmaUtil).
// Rectangle-preserving XCD decode. Fused bf16-MFMA gates + fp32 LSTM cell.

#define NN 4096
#define BB 32
#define HH 64

typedef __attribute__((ext_vector_type(8))) short short8;
typedef __attribute__((ext_vector_type(4))) float f32x4;

#define BARRIER asm volatile("s_barrier" ::: "memory")
#define VMCNT(n) asm volatile("s_waitcnt vmcnt(" #n ")" ::: "memory")

__device__ __forceinline__ unsigned short f2bf(float f) {
  unsigned int u = __float_as_uint(f);
  u += 0x7fffu + ((u >> 16) & 1u);
  return (unsigned short)(u >> 16);
}

// ---------------- G fp32 -> bf16 (vectorized) ----------------
__global__ __launch_bounds__(256) void cvt_kernel(const float* __restrict__ in,
                                                  unsigned short* __restrict__ out,
                                                  long n4) {
  long i = (long)blockIdx.x * 256 + threadIdx.x;
  if (i >= n4) return;
  float4 v = ((const float4*)in)[i];
  ushort4 o;
  o.x = f2bf(v.x); o.y = f2bf(v.y); o.z = f2bf(v.z); o.w = f2bf(v.w);
  ((ushort4*)out)[i] = o;
}

// ---------------- zero supp0 pad cols (240..255 of each 256-col row) -------
__global__ __launch_bounds__(256) void pad_zero(unsigned short* __restrict__ supp) {
  int i = blockIdx.x * 256 + threadIdx.x;   // 262144 short8 units
  int row = i >> 1;
  int half = i & 1;
  short8 z = {};
  *(short8*)&supp[(long)row * 256 + 240 + half * 8] = z;
}

// ---------------- pack comb0^T : [2560][4096] bf16 ----------------
__global__ __launch_bounds__(256) void pack_comb0(const float* __restrict__ x,
                                                  const float* __restrict__ h,
                                                  unsigned short* __restrict__ cT) {
  __shared__ float tile[80][65];
  const int m0 = blockIdx.x * 64;
  const int b = blockIdx.y;
  const int t = threadIdx.x;
  for (int i = t; i < 64 * 16; i += 256) {
    int m = i >> 4, p = i & 15;
    tile[p][m] = x[((long)b * NN + m0 + m) * 16 + p];
  }
  for (int i = t; i < 64 * 64; i += 256) {
    int m = i >> 6, p = i & 63;
    tile[16 + p][m] = h[((long)b * NN + m0 + m) * 64 + p];
  }
  __syncthreads();
  for (int i = t; i < 80 * 64; i += 256) {
    int p = i >> 6, m = i & 63;
    cT[((long)(b * 80 + p)) * NN + m0 + m] = f2bf(tile[p][m]);
  }
}

// ---------------- pack h1 into comb1^T cols [b*128+64 ..] ----------------
__global__ __launch_bounds__(256) void pack_h1(const float* __restrict__ h,
                                               unsigned short* __restrict__ cT) {
  __shared__ float tile[64][65];
  const int m0 = blockIdx.x * 64;
  const int b = blockIdx.y;
  const int t = threadIdx.x;
  for (int i = t; i < 64 * 64; i += 256) {
    int m = i >> 6, p = i & 63;
    tile[p][m] = h[((long)b * NN + m0 + m) * 64 + p];
  }
  __syncthreads();
  for (int i = t; i < 64 * 64; i += 256) {
    int p = i >> 6, m = i & 63;
    cT[((long)(b * 128 + 64 + p)) * NN + m0 + m] = f2bf(tile[p][m]);
  }
}

// ---------------- W [KP][256] fp32 -> Wt [256][SP] bf16 (zero-pad) --------
__global__ __launch_bounds__(256) void prep_wt(const float* __restrict__ W,
                                               unsigned short* __restrict__ Wt,
                                               int KP, int SP) {
  int c = blockIdx.x;
  for (int k = threadIdx.x; k < SP; k += blockDim.x)
    Wt[(long)c * SP + k] = (k < KP) ? f2bf(W[(long)k * 256 + c]) : (unsigned short)0;
}

// ---------------- supp GEMM: 256x256, BK=64, 8 waves, flow schedule --------
// out[b,n,k,p] = sum_m G[k][n][m] * combT[b*P+p][m]
// LDS 128 KiB = 2 dbuf x (A 32K + B 32K). Per K-tile: one inter-barrier
// window containing {all 24 ds_reads + 4 mmac clusters interleaved + 4
// half-tile stages for t+1}; VMCNT(0)+BARRIER at tile end only.
template <int P, int SP, int RPK>
__global__ __launch_bounds__(512, 2) void gemm_flow(const unsigned short* __restrict__ Gb,
                                                    const unsigned short* __restrict__ BT,
                                                    unsigned short* __restrict__ supp) {
  __shared__ short lds[2][2][256 * 64];  // 128 KiB
  const int t = threadIdx.x;
  const int w = t >> 6;
  const int lane = t & 63;
  const int lr = lane & 15;
  const int q = lane >> 4;
  const int wm = w >> 2;   // 0..1 : row half (128 rows)
  const int wn = w & 3;    // 0..3 : col band (64 cols)

  const int bid = blockIdx.x;
  const int xcd = bid & 7;
  const int rank = bid >> 3;
  const int kh = rank / RPK;
  const int jr = rank - kh * RPK;
  const int bm = xcd * 2 + (jr & 1);
  const int bc = jr >> 1;

  const short* Ag = (const short*)Gb + (long)kh * NN * NN + (long)bm * 256 * NN;
  const short* Bg = (const short*)BT + (long)bc * 256 * NN;

  // stage one row-half (128 rows x 64 k); linear LDS dest + XOR-swizzled src.
  auto stage = [&](int mat, int buf, int kt, int half) {
    const short* base = (mat ? Bg : Ag) + kt * 64;
#pragma unroll
    for (int j = 0; j < 2; ++j) {
      int L = j * 512 + t;
      int rl = L >> 3;
      int sl = L & 7;
      int r = half * 128 + rl;
      int s0 = sl ^ (r & 7);
      short* dst = &lds[buf][mat][(half * 1024 + j * 512 + w * 64) * 8];
      __builtin_amdgcn_global_load_lds(
          (const __attribute__((address_space(1))) void*)(base + (long)r * NN + s0 * 8),
          (__attribute__((address_space(3))) void*)dst, 16, 0, 0);
    }
  };

  f32x4 acc[8][4] = {};
  short8 a4[4], bfr[4];

  auto rdA = [&](int buf, int u, int ks) {
#pragma unroll
    for (int mi = 0; mi < 4; ++mi) {
      int row = wm * 128 + (u * 4 + mi) * 16 + lr;
      int slot = (ks * 4 + q) ^ (row & 7);
      a4[mi] = *(const short8*)&lds[buf][0][row * 64 + slot * 8];
    }
  };
  auto rdB = [&](int buf, int ks) {
#pragma unroll
    for (int ni = 0; ni < 4; ++ni) {
      int row = wn * 64 + ni * 16 + lr;
      int slot = (ks * 4 + q) ^ (row & 7);
      bfr[ni] = *(const short8*)&lds[buf][1][row * 64 + slot * 8];
    }
  };
  auto mmac = [&](int u) {
    __builtin_amdgcn_s_setprio(1);
#pragma unroll
    for (int mi = 0; mi < 4; ++mi)
#pragma unroll
      for (int ni = 0; ni < 4; ++ni)
        acc[u * 4 + mi][ni] =
            __builtin_amdgcn_mfma_f32_16x16x32_bf16(a4[mi], bfr[ni], acc[u * 4 + mi][ni], 0, 0, 0);
    __builtin_amdgcn_s_setprio(0);
  };

  // prologue: tile0 (all 4 halves) -> buf0.
  stage(0, 0, 0, 0); stage(0, 0, 0, 1);
  stage(1, 0, 0, 0); stage(1, 0, 0, 1);
  VMCNT(0);
  BARRIER;

  for (int g = 0; g < 32; ++g) {
    const int tk = 2 * g;
    // ---- tile tk (buf0); stage tile tk+1 -> buf1 ----
    rdB(0, 0); rdA(0, 0, 0);
    stage(0, 1, tk + 1, 0); stage(0, 1, tk + 1, 1);   // A(t+1)
    mmac(0);
    rdA(0, 1, 0);
    stage(1, 1, tk + 1, 0);                            // Btop(t+1)
    mmac(1);
    rdB(0, 1); rdA(0, 0, 1);
    stage(1, 1, tk + 1, 1);                            // Bbot(t+1)
    mmac(0);
    rdA(0, 1, 1);
    mmac(1);
    VMCNT(0);
    BARRIER;
    // ---- tile tk+1 (buf1); stage tile tk+2 -> buf0 ----
    rdB(1, 0); rdA(1, 0, 0);
    if (tk + 2 < 64) { stage(0, 0, tk + 2, 0); stage(0, 0, tk + 2, 1); }
    mmac(0);
    rdA(1, 1, 0);
    if (tk + 2 < 64) stage(1, 0, tk + 2, 0);
    mmac(1);
    rdB(1, 1); rdA(1, 0, 1);
    if (tk + 2 < 64) stage(1, 0, tk + 2, 1);
    mmac(0);
    rdA(1, 1, 1);
    mmac(1);
    VMCNT(0);
    BARRIER;
  }

  // Epilogue: D col=lane&15, row=(lane>>4)*4+i (verified); plain stores.
#pragma unroll
  for (int mi = 0; mi < 8; ++mi) {
#pragma unroll
    for (int ni = 0; ni < 4; ++ni) {
      int ccol = bc * 256 + wn * 64 + ni * 16 + lr;
      int b = ccol / P;
      int p = ccol - b * P;
#pragma unroll
      for (int i = 0; i < 4; ++i) {
        int n = bm * 256 + wm * 128 + mi * 16 + q * 4 + i;
        supp[((long)(b * NN + n)) * SP + kh * P + p] = f2bf(acc[mi][ni][i]);
      }
    }
  }
}

// ---------------- gates GEMM + LSTM cell, fused (32 tokens/wave) ----------
template <int SP, bool WBF, bool WH2>
__global__ __launch_bounds__(256) void gates_cell(const unsigned short* __restrict__ supp,
                                                  const unsigned short* __restrict__ Wt,
                                                  const float* __restrict__ bias,
                                                  const float* __restrict__ c_pre,
                                                  float* __restrict__ h_out,
                                                  float* __restrict__ c_out,
                                                  float* __restrict__ h_out2,
                                                  unsigned short* __restrict__ h_bf) {
  const int t = threadIdx.x;
  const int w = t >> 6;
  const int lane = t & 63;
  const int lr = lane & 15;
  const int q = lane >> 4;
  const long tok0 = (long)blockIdx.x * 128 + w * 32;
  f32x4 acc[2][16] = {};

  const short* sp0 = (const short*)supp + (tok0 + lr) * SP + q * 8;
  const short* sp1 = sp0 + 16 * SP;
  const short* wt = (const short*)Wt + (long)lr * SP + q * 8;
  for (int kk = 0; kk < SP / 32; ++kk) {
    short8 a0 = *(const short8*)(sp0 + kk * 32);
    short8 a1 = *(const short8*)(sp1 + kk * 32);
#pragma unroll
    for (int nf = 0; nf < 16; ++nf) {
      short8 b = *(const short8*)(wt + (long)nf * 16 * SP + kk * 32);
      acc[0][nf] = __builtin_amdgcn_mfma_f32_16x16x32_bf16(a0, b, acc[0][nf], 0, 0, 0);
      acc[1][nf] = __builtin_amdgcn_mfma_f32_16x16x32_bf16(a1, b, acc[1][nf], 0, 0, 0);
    }
  }
#pragma unroll
  for (int gi = 0; gi < 2; ++gi) {
#pragma unroll
    for (int i = 0; i < 4; ++i) {
      long tok = tok0 + gi * 16 + q * 4 + i;
      int bidx = (int)(tok >> 12);
      int n = (int)(tok & (NN - 1));
#pragma unroll
      for (int j = 0; j < 4; ++j) {
        int h = lr + 16 * j;
        float gi_ = acc[gi][j][i] + bias[h];
        float gf_ = acc[gi][j + 4][i] + bias[h + 64];
        float go_ = acc[gi][j + 8][i] + bias[h + 128];
        float gg_ = acc[gi][j + 12][i] + bias[h + 192];
        float cp = c_pre[tok * 64 + h];
        float ig = 1.f / (1.f + __expf(-gi_));
        float fg = 1.f / (1.f + __expf(-gf_));
        float og = 1.f / (1.f + __expf(-go_));
        float ct = fg * cp + ig * tanhf(gg_);
        float ht = og * tanhf(ct);
        c_out[tok * 64 + h] = ct;
        h_out[tok * 64 + h] = ht;
        if (WH2) h_out2[tok * 64 + h] = ht;
        if (WBF) h_bf[((long)(bidx * 128 + h)) * NN + n] = f2bf(ht);
      }
    }
  }
}

extern "C" void kernel_launch(void* const* d_in, const int* in_sizes, int n_in,
                              void* d_out, int out_size, void* d_ws, size_t ws_size,
                              hipStream_t stream) {
  const float* G  = (const float*)d_in[0];
  const float* x_t = (const float*)d_in[1];
  const float* h0 = (const float*)d_in[2];
  const float* h1 = (const float*)d_in[3];
  const float* c0 = (const float*)d_in[4];
  const float* c1 = (const float*)d_in[5];
  const float* W0 = (const float*)d_in[6];
  const float* b0 = (const float*)d_in[7];
  const float* W1 = (const float*)d_in[8];
  const float* b1 = (const float*)d_in[9];
  float* out = (float*)d_out;
  const long M = 8388608L;  // B*N*H

  char* ws = (char*)d_ws;
  unsigned short* Gb    = (unsigned short*)(ws);               // 100,663,296 B
  unsigned short* c0T   = (unsigned short*)(ws + 100663296L);  //  20,971,520 B
  unsigned short* c1T   = (unsigned short*)(ws + 121634816L);  //  33,554,432 B
  unsigned short* supp1 = (unsigned short*)(ws + 155189248L);  // 100,663,296 B
  unsigned short* supp0 = supp1;  // aliased (dead before gemm1 writes)
  unsigned short* Wt0   = (unsigned short*)(ws + 255852544L);
  unsigned short* Wt1   = (unsigned short*)(ws + 255983616L);

  // zero layer-0 supp pad cols only (4 MB instead of 64 MB memset)
  pad_zero<<<1024, 256, 0, stream>>>(supp0);

  cvt_kernel<<<49152, 256, 0, stream>>>(G, Gb, 12582912L);
  pack_comb0<<<dim3(64, 32), 256, 0, stream>>>(x_t, h0, c0T);
  pack_h1<<<dim3(64, 32), 256, 0, stream>>>(h1, c1T);
  prep_wt<<<dim3(256), 256, 0, stream>>>(W0, Wt0, 240, 256);
  prep_wt<<<dim3(256), 256, 0, stream>>>(W1, Wt1, 384, 384);

  // layer 0: 16 bm x 10 bc x 3 kh = 480 blocks; RPK = 20 ranks per kh
  gemm_flow<80, 256, 20><<<480, 512, 0, stream>>>(Gb, c0T, supp0);
  gates_cell<256, true, false><<<1024, 256, 0, stream>>>(
      supp0, Wt0, b0, c0, out + M, out + 3 * M, nullptr, c1T);
  // layer 1: 16 bm x 16 bc x 3 kh = 768 blocks; RPK = 32
  gemm_flow<128, 384, 32><<<768, 512, 0, stream>>>(Gb, c1T, supp1);
  gates_cell<384, false, true><<<1024, 256, 0, stream>>>(
      supp1, Wt1, b1, c1, out, out + 4 * M, out + 2 * M, nullptr);
}